// Round 5
// baseline (121.918 us; speedup 1.0000x reference)
//
#include <hip/hip_runtime.h>

typedef float f32x4 __attribute__((ext_vector_type(4)));
typedef float f32x16 __attribute__((ext_vector_type(16)));
typedef unsigned int u32x4 __attribute__((ext_vector_type(4)));
typedef __bf16 bf16x8 __attribute__((ext_vector_type(8)));
typedef unsigned short ushort_t;

#define NEG2 (-144269.5f)   /* -1e5 * log2(e) */
#define SCLQ (0.18033688f)  /* 0.125 * log2(e) */
#define THR2 (11.5f)        /* defer-max threshold, ~8 nats in bits */

constexpr int Ss = 2048, Ee = 1024, Hh = 64;

static __device__ __forceinline__ ushort_t f2bfu(float f) {
  return __builtin_bit_cast(ushort_t, (__bf16)f);
}
static __device__ __forceinline__ f32x4 mfma16(bf16x8 a, bf16x8 b, f32x4 c) {
  return __builtin_amdgcn_mfma_f32_16x16x32_bf16(a, b, c, 0, 0, 0);
}
static __device__ __forceinline__ f32x16 mfma32(bf16x8 a, bf16x8 b, f32x16 c) {
  return __builtin_amdgcn_mfma_f32_32x32x16_bf16(a, b, c, 0, 0, 0);
}
static __device__ __forceinline__ unsigned cvtpk(float a, float b) {
  unsigned r;
  asm("v_cvt_pk_bf16_f32 %0, %1, %2" : "=v"(r) : "v"(a), "v"(b));
  return r;
}
// NOTE: only call with a,b holding DIFFERENT values (R3 bug: identical values
// tie to one phys reg -> in-place self-swap). Cross-half reductions use __shfl_xor.
static __device__ __forceinline__ void swap32(unsigned& a, unsigned& b) {
  asm("v_permlane32_swap_b32 %0, %1" : "+v"(a), "+v"(b));
}

// ---------------- weight transpose + bf16 convert: Wt[m][h][e] ----------------
__global__ __launch_bounds__(256) void k_wtrans(const float* __restrict__ Wq,
                                                const float* __restrict__ Wk,
                                                const float* __restrict__ Wv,
                                                ushort_t* __restrict__ Wt) {
  __shared__ float tile[64][65];
  const float* W = (blockIdx.y == 0) ? Wq : (blockIdx.y == 1 ? Wk : Wv);
  int kt = blockIdx.x, t = threadIdx.x;
  int r = t >> 2, cq = t & 3;
  const float* src = W + (kt * 64 + r) * Hh + cq * 16;
#pragma unroll
  for (int j = 0; j < 16; j += 4) {
    float4 v = *reinterpret_cast<const float4*>(src + j);
    tile[r][cq * 16 + j + 0] = v.x;
    tile[r][cq * 16 + j + 1] = v.y;
    tile[r][cq * 16 + j + 2] = v.z;
    tile[r][cq * 16 + j + 3] = v.w;
  }
  __syncthreads();
  int n = t >> 2, kq = t & 3;
  ushort_t ob[16];
#pragma unroll
  for (int j = 0; j < 16; ++j) ob[j] = f2bfu(tile[kq * 16 + j][n]);
  ushort_t* dst = Wt + ((size_t)blockIdx.y * 64 + n) * Ee + kt * 64 + kq * 16;
  reinterpret_cast<uint4*>(dst)[0] = reinterpret_cast<uint4*>(ob)[0];
  reinterpret_cast<uint4*>(dst)[1] = reinterpret_cast<uint4*>(ob)[1];
}

// ---------------- fused QKV projection: 1024 blocks x 4 waves x 16 rows ----------------
// Wave w owns output cols [w*48, w*48+48): tiles T = w*3+nt, m=T>>2 (q/k/v), h=(T&3)*16+c.
// hs loads double-buffered (named pa*/pb*, unroll-2) so HBM latency hides under
// cvt + L2 weight loads + MFMA; __launch_bounds__(256,4) -> VGPR cap 128, 4 blocks/CU.
// q stored [B*S][64] bf16 PRE-SCALED by 0.125*log2e; k [B*S][64]; v transposed vt[b][h][s].
// Also emits pen[b][2][S] f32: penA (active-q xor term), penP (pad-q term).
__global__ __launch_bounds__(256, 4) void k_proj(const float* __restrict__ hs,
                                                 const float* __restrict__ bq,
                                                 const float* __restrict__ bk,
                                                 const float* __restrict__ bv,
                                                 const ushort_t* __restrict__ Wt,
                                                 const int* __restrict__ am,
                                                 ushort_t* __restrict__ q,
                                                 ushort_t* __restrict__ k,
                                                 ushort_t* __restrict__ vt,
                                                 float* __restrict__ pen) {
  int t = threadIdx.x, w = t >> 6, l = t & 63, g = l >> 4, c = l & 15;
  int row0 = blockIdx.x * 16;
  const float* ap = hs + (size_t)(row0 + c) * Ee + g * 8;
  const ushort_t* wp0 = Wt + (size_t)(w * 48 + c) * Ee + g * 8;

  f32x4 acc[3];
#pragma unroll
  for (int nt = 0; nt < 3; ++nt) acc[nt] = f32x4{0.f, 0.f, 0.f, 0.f};

  float4 pa0, pa1, pa2, pa3, pb0, pb1, pb2, pb3;
  pa0 = *reinterpret_cast<const float4*>(ap + 0);
  pa1 = *reinterpret_cast<const float4*>(ap + 4);
  pa2 = *reinterpret_cast<const float4*>(ap + 32);
  pa3 = *reinterpret_cast<const float4*>(ap + 36);

  auto compute = [&](int kk, float4 r0, float4 r1, float4 r2, float4 r3) {
    bf16x8 af0, af1;
    af0[0] = (__bf16)r0.x; af0[1] = (__bf16)r0.y; af0[2] = (__bf16)r0.z; af0[3] = (__bf16)r0.w;
    af0[4] = (__bf16)r1.x; af0[5] = (__bf16)r1.y; af0[6] = (__bf16)r1.z; af0[7] = (__bf16)r1.w;
    af1[0] = (__bf16)r2.x; af1[1] = (__bf16)r2.y; af1[2] = (__bf16)r2.z; af1[3] = (__bf16)r2.w;
    af1[4] = (__bf16)r3.x; af1[5] = (__bf16)r3.y; af1[6] = (__bf16)r3.z; af1[7] = (__bf16)r3.w;
#pragma unroll
    for (int nt = 0; nt < 3; ++nt) {
      const ushort_t* wp = wp0 + (size_t)nt * 16 * Ee + kk;
      bf16x8 b0 = *reinterpret_cast<const bf16x8*>(wp);
      bf16x8 b1 = *reinterpret_cast<const bf16x8*>(wp + 32);
      acc[nt] = mfma16(af0, b0, acc[nt]);
      acc[nt] = mfma16(af1, b1, acc[nt]);
    }
  };

  for (int kk = 0; kk < Ee; kk += 128) {
    // prefetch B half (kk+64)
    pb0 = *reinterpret_cast<const float4*>(ap + kk + 64);
    pb1 = *reinterpret_cast<const float4*>(ap + kk + 68);
    pb2 = *reinterpret_cast<const float4*>(ap + kk + 96);
    pb3 = *reinterpret_cast<const float4*>(ap + kk + 100);
    compute(kk, pa0, pa1, pa2, pa3);
    // prefetch next A half (kk+128)
    if (kk + 128 < Ee) {
      pa0 = *reinterpret_cast<const float4*>(ap + kk + 128);
      pa1 = *reinterpret_cast<const float4*>(ap + kk + 132);
      pa2 = *reinterpret_cast<const float4*>(ap + kk + 160);
      pa3 = *reinterpret_cast<const float4*>(ap + kk + 164);
    }
    compute(kk + 64, pb0, pb1, pb2, pb3);
  }

#pragma unroll
  for (int nt = 0; nt < 3; ++nt) {
    int T = w * 3 + nt;
    int m = T >> 2;
    int h = (T & 3) * 16 + c;
    const float* bias = (m == 0) ? bq : ((m == 1) ? bk : bv);
    float bb = bias[h];
#pragma unroll
    for (int i = 0; i < 4; ++i) {
      int row = row0 + g * 4 + i;
      float val = acc[nt][i] + bb;
      if (m == 0) {
        q[(size_t)row * Hh + h] = f2bfu(val * SCLQ);
      } else if (m == 1) {
        k[(size_t)row * Hh + h] = f2bfu(val);
      } else {
        int bi = row >> 11, s2 = row & 2047;
        vt[((size_t)(bi * 64 + h)) * Ss + s2] = f2bfu(val);
      }
    }
  }

  if (t < 16) {
    int grow = row0 + t;
    int bi = grow >> 11, s2 = grow & 2047;
    int mv = am[grow];
    pen[((size_t)bi * 2 + 0) * Ss + s2] = mv ? 0.f : NEG2;
    pen[((size_t)bi * 2 + 1) * Ss + s2] = mv ? NEG2 : 0.f;
  }
}

// ---------------- fused masked flash attention, swapped-QK 32x32, in-register softmax ----
// Block: 32 q-rows of one batch, 4 waves split keys (512 each, 16 tiles of 32).
// Lane owns one q-row (lo = l&31): softmax = 15 in-lane max/sum + 1 cross-half shfl.
// P -> PV A-frags via 8 cvt_pk + 4 permlane32_swap. Defer-max (T13) makes O-rescale rare.
__global__ __launch_bounds__(256) void k_attn(const ushort_t* __restrict__ qs,
                                              const ushort_t* __restrict__ km,
                                              const ushort_t* __restrict__ vt,
                                              const int* __restrict__ am,
                                              const float* __restrict__ pen,
                                              float* __restrict__ out) {
  __shared__ float obuf[4][32][64];
  __shared__ float mls[4][32], lls[4][32];

  int t = threadIdx.x, w = t >> 6, l = t & 63, lo = l & 31, hi = l >> 5;
  int b = blockIdx.y, q0 = blockIdx.x * 32;

  // Q B-frags (hoisted): lane holds Q[q0+lo][c*16 + hi*8 + j]
  const ushort_t* qp = qs + ((size_t)(b * Ss + q0 + lo)) * Hh + hi * 8;
  bf16x8 qf[4];
#pragma unroll
  for (int c = 0; c < 4; ++c) qf[c] = *reinterpret_cast<const bf16x8*>(qp + c * 16);

  int mq = am[b * Ss + q0 + lo];
  float negq = mq ? NEG2 : 0.f;
  const float* psel = pen + ((size_t)b * 2 + (mq ? 0 : 1)) * Ss;

  float m = -3.0e38f, ll = 0.f;
  f32x16 o0 = {0.f, 0.f, 0.f, 0.f, 0.f, 0.f, 0.f, 0.f, 0.f, 0.f, 0.f, 0.f, 0.f, 0.f, 0.f, 0.f};
  f32x16 o1 = o0;
  const f32x16 z16 = o0;

  const int kvbeg = w * 512;
  for (int it = 0; it < 16; ++it) {
    int kv0 = kvbeg + it * 32;

    // K A-frags: lane holds K[kv0+lo][c*16 + hi*8 + j]
    const ushort_t* kp = km + ((size_t)(b * Ss + kv0 + lo)) * Hh + hi * 8;
    bf16x8 kf0 = *reinterpret_cast<const bf16x8*>(kp);
    bf16x8 kf1 = *reinterpret_cast<const bf16x8*>(kp + 16);
    bf16x8 kf2 = *reinterpret_cast<const bf16x8*>(kp + 32);
    bf16x8 kf3 = *reinterpret_cast<const bf16x8*>(kp + 48);

    // V B-frags: lane holds V[kv0 + c2*16 + hi*8 + j][dt*32 + lo] from vt[b][d][s]
    const ushort_t* vp0 = vt + ((size_t)(b * 64 + lo)) * Ss + kv0 + hi * 8;
    const ushort_t* vp1 = vt + ((size_t)(b * 64 + 32 + lo)) * Ss + kv0 + hi * 8;
    bf16x8 vf00 = *reinterpret_cast<const bf16x8*>(vp0);
    bf16x8 vf10 = *reinterpret_cast<const bf16x8*>(vp0 + 16);
    bf16x8 vf01 = *reinterpret_cast<const bf16x8*>(vp1);
    bf16x8 vf11 = *reinterpret_cast<const bf16x8*>(vp1 + 16);

    // penalty vectors: reg r -> key kv0 + (r&3) + 8*(r>>2) + 4*hi
    f32x4 pv[4];
#pragma unroll
    for (int j = 0; j < 4; ++j)
      pv[j] = *reinterpret_cast<const f32x4*>(psel + kv0 + j * 8 + hi * 4);

    // ---- scores: D[key][q], key = (r&3)+8*(r>>2)+4*hi, q = lo ----
    f32x16 sc = mfma32(kf0, qf[0], z16);
    sc = mfma32(kf1, qf[1], sc);
    sc = mfma32(kf2, qf[2], sc);
    sc = mfma32(kf3, qf[3], sc);

    if (kv0 == q0) {  // straddle tile: per-reg causal
#pragma unroll
      for (int r = 0; r < 16; ++r) {
        int kr = (r & 3) + 8 * (r >> 2) + 4 * hi;
        float pc = (kr > lo) ? negq : 0.f;
        sc[r] += pv[r >> 2][r & 3] + pc;
      }
    } else {
      float addt = (kv0 > q0) ? negq : 0.f;
#pragma unroll
      for (int r = 0; r < 16; ++r) sc[r] += pv[r >> 2][r & 3] + addt;
    }

    // ---- row max (in-lane tree + cross-half shfl) ----
    float pm01 = fmaxf(sc[0], sc[1]), pm23 = fmaxf(sc[2], sc[3]);
    float pm45 = fmaxf(sc[4], sc[5]), pm67 = fmaxf(sc[6], sc[7]);
    float pm89 = fmaxf(sc[8], sc[9]), pmab = fmaxf(sc[10], sc[11]);
    float pmcd = fmaxf(sc[12], sc[13]), pmef = fmaxf(sc[14], sc[15]);
    float pm = fmaxf(fmaxf(fmaxf(pm01, pm23), fmaxf(pm45, pm67)),
                     fmaxf(fmaxf(pm89, pmab), fmaxf(pmcd, pmef)));
    pm = fmaxf(pm, __shfl_xor(pm, 32));

    // ---- defer-max: rescale only when the running max grows past THR2 ----
    if (!__all(pm <= m + THR2)) {
      float mn = fmaxf(m, pm);
      float alpha = __builtin_amdgcn_exp2f(m - mn);
      m = mn;
      ll *= alpha;
      int ia = __builtin_bit_cast(int, alpha);
#pragma unroll
      for (int r = 0; r < 16; ++r) {
        int qrow = (r & 3) + 8 * (r >> 2) + 4 * hi;
        float af = __builtin_bit_cast(float, __builtin_amdgcn_ds_bpermute(qrow << 2, ia));
        o0[r] *= af;
        o1[r] *= af;
      }
    }

    // ---- p = exp2(sc - m), row sum ----
    float p[16];
    float ts = 0.f;
#pragma unroll
    for (int r = 0; r < 16; ++r) {
      p[r] = __builtin_amdgcn_exp2f(sc[r] - m);
      ts += p[r];
    }
    ts += __shfl_xor(ts, 32);
    ll += ts;

    // ---- P -> PV A-frags: 8 cvt_pk + 4 permlane32_swap (distinct values: safe) ----
    unsigned x0 = cvtpk(p[0], p[1]), y0 = cvtpk(p[2], p[3]);
    unsigned z0 = cvtpk(p[4], p[5]), w0 = cvtpk(p[6], p[7]);
    swap32(x0, z0);
    swap32(y0, w0);
    unsigned x1 = cvtpk(p[8], p[9]), y1 = cvtpk(p[10], p[11]);
    unsigned z1 = cvtpk(p[12], p[13]), w1 = cvtpk(p[14], p[15]);
    swap32(x1, z1);
    swap32(y1, w1);
    bf16x8 pa0 = __builtin_bit_cast(bf16x8, u32x4{x0, y0, z0, w0});
    bf16x8 pa1 = __builtin_bit_cast(bf16x8, u32x4{x1, y1, z1, w1});

    // ---- PV: D[q][d] ----
    o0 = mfma32(pa0, vf00, o0);
    o0 = mfma32(pa1, vf10, o0);
    o1 = mfma32(pa0, vf01, o1);
    o1 = mfma32(pa1, vf11, o1);
  }

  // ---- stash partials ----
#pragma unroll
  for (int r = 0; r < 16; ++r) {
    int qrow = (r & 3) + 8 * (r >> 2) + 4 * hi;
    obuf[w][qrow][lo] = o0[r];
    obuf[w][qrow][32 + lo] = o1[r];
  }
  if (hi == 0) {
    mls[w][lo] = m;
    lls[w][lo] = ll;
  }
  __syncthreads();

  // ---- combine 4 KV-split partials: thread -> (qrow = t>>3, 8 d-cols) ----
  int qr = t >> 3, dg = t & 7;
  float mg = fmaxf(fmaxf(mls[0][qr], mls[1][qr]), fmaxf(mls[2][qr], mls[3][qr]));
  float lg = 0.f, sw[4];
#pragma unroll
  for (int ww = 0; ww < 4; ++ww) {
    sw[ww] = __builtin_amdgcn_exp2f(mls[ww][qr] - mg);
    lg += lls[ww][qr] * sw[ww];
  }
  float a8[8] = {0.f, 0.f, 0.f, 0.f, 0.f, 0.f, 0.f, 0.f};
#pragma unroll
  for (int ww = 0; ww < 4; ++ww) {
    float4 c0 = *reinterpret_cast<const float4*>(&obuf[ww][qr][dg * 8]);
    float4 c1 = *reinterpret_cast<const float4*>(&obuf[ww][qr][dg * 8 + 4]);
    a8[0] += c0.x * sw[ww]; a8[1] += c0.y * sw[ww];
    a8[2] += c0.z * sw[ww]; a8[3] += c0.w * sw[ww];
    a8[4] += c1.x * sw[ww]; a8[5] += c1.y * sw[ww];
    a8[6] += c1.z * sw[ww]; a8[7] += c1.w * sw[ww];
  }
  float inv = 1.f / lg;
  float4 r0 = {a8[0] * inv, a8[1] * inv, a8[2] * inv, a8[3] * inv};
  float4 r1 = {a8[4] * inv, a8[5] * inv, a8[6] * inv, a8[7] * inv};
  float* op = out + ((size_t)(b * Ss + q0 + qr)) * Hh + dg * 8;
  *reinterpret_cast<float4*>(op) = r0;
  *reinterpret_cast<float4*>(op + 4) = r1;
}

extern "C" void kernel_launch(void* const* d_in, const int* in_sizes, int n_in,
                              void* d_out, int out_size, void* d_ws, size_t ws_size,
                              hipStream_t stream) {
  const float* hs = (const float*)d_in[0];
  const int* am = (const int*)d_in[1];
  const float* Wq = (const float*)d_in[2];
  const float* bq = (const float*)d_in[3];
  const float* Wk = (const float*)d_in[4];
  const float* bk = (const float*)d_in[5];
  const float* Wv = (const float*)d_in[6];
  const float* bv = (const float*)d_in[7];
  float* out = (float*)d_out;

  char* ws = (char*)d_ws;
  ushort_t* qsp = (ushort_t*)(ws + 0);                  // 2 MB: [B*S][64] bf16, scaled
  ushort_t* kp = (ushort_t*)(ws + (2u << 20));          // 2 MB: [B*S][64] bf16
  ushort_t* vtp = (ushort_t*)(ws + (4u << 20));         // 2 MB: [B][64][S] bf16 (V^T)
  ushort_t* wtp = (ushort_t*)(ws + (6u << 20));         // 384 KB: [3][64][1024] bf16 (W^T)
  float* penp = (float*)(ws + (6u << 20) + (512u << 10));  // 128 KB: [B][2][S] f32

  k_wtrans<<<dim3(16, 3), 256, 0, stream>>>(Wq, Wk, Wv, wtp);
  k_proj<<<dim3(1024), 256, 0, stream>>>(hs, bq, bk, bv, wtp, am, qsp, kp, vtp, penp);
  k_attn<<<dim3(64, 8), 256, 0, stream>>>(qsp, kp, vtp, am, penp, out);
}

// Round 6
// 69.986 us; speedup vs baseline: 1.7420x; 1.7420x over previous
//
#include <hip/hip_runtime.h>

typedef float f32x4 __attribute__((ext_vector_type(4)));
typedef float f32x16 __attribute__((ext_vector_type(16)));
typedef unsigned int u32x4 __attribute__((ext_vector_type(4)));
typedef __bf16 bf16x8 __attribute__((ext_vector_type(8)));
typedef unsigned short ushort_t;

#define NEG2 (-144269.5f)   /* -1e5 * log2(e) */
#define SCLQ (0.18033688f)  /* 0.125 * log2(e) */
#define THR2 (11.5f)        /* defer-max threshold, ~8 nats in bits */

constexpr int Ss = 2048, Ee = 1024, Hh = 64;

static __device__ __forceinline__ ushort_t f2bfu(float f) {
  return __builtin_bit_cast(ushort_t, (__bf16)f);
}
static __device__ __forceinline__ f32x4 mfma16(bf16x8 a, bf16x8 b, f32x4 c) {
  return __builtin_amdgcn_mfma_f32_16x16x32_bf16(a, b, c, 0, 0, 0);
}
static __device__ __forceinline__ f32x16 mfma32(bf16x8 a, bf16x8 b, f32x16 c) {
  return __builtin_amdgcn_mfma_f32_32x32x16_bf16(a, b, c, 0, 0, 0);
}
static __device__ __forceinline__ unsigned cvtpk(float a, float b) {
  unsigned r;
  asm("v_cvt_pk_bf16_f32 %0, %1, %2" : "=v"(r) : "v"(a), "v"(b));
  return r;
}
// NOTE: only call with a,b holding DIFFERENT values (R3 bug: identical values
// tie to one phys reg -> in-place self-swap). Cross-half reductions use __shfl_xor.
static __device__ __forceinline__ void swap32(unsigned& a, unsigned& b) {
  asm("v_permlane32_swap_b32 %0, %1" : "+v"(a), "+v"(b));
}

// ---------------- weight transpose + bf16 convert: Wt[m][h][e] ----------------
__global__ __launch_bounds__(256) void k_wtrans(const float* __restrict__ Wq,
                                                const float* __restrict__ Wk,
                                                const float* __restrict__ Wv,
                                                ushort_t* __restrict__ Wt) {
  __shared__ float tile[64][65];
  const float* W = (blockIdx.y == 0) ? Wq : (blockIdx.y == 1 ? Wk : Wv);
  int kt = blockIdx.x, t = threadIdx.x;
  int r = t >> 2, cq = t & 3;
  const float* src = W + (kt * 64 + r) * Hh + cq * 16;
#pragma unroll
  for (int j = 0; j < 16; j += 4) {
    float4 v = *reinterpret_cast<const float4*>(src + j);
    tile[r][cq * 16 + j + 0] = v.x;
    tile[r][cq * 16 + j + 1] = v.y;
    tile[r][cq * 16 + j + 2] = v.z;
    tile[r][cq * 16 + j + 3] = v.w;
  }
  __syncthreads();
  int n = t >> 2, kq = t & 3;
  ushort_t ob[16];
#pragma unroll
  for (int j = 0; j < 16; ++j) ob[j] = f2bfu(tile[kq * 16 + j][n]);
  ushort_t* dst = Wt + ((size_t)blockIdx.y * 64 + n) * Ee + kt * 64 + kq * 16;
  reinterpret_cast<uint4*>(dst)[0] = reinterpret_cast<uint4*>(ob)[0];
  reinterpret_cast<uint4*>(dst)[1] = reinterpret_cast<uint4*>(ob)[1];
}

// ---------------- fused QKV projection: LDS-staged, double-buffered ----------------
// 256 blocks x 512 threads. Tile: 64 rows x 192 cols, K-step 64 (16 steps).
// hs staged f32->bf16 into LDS [64][72]; Wt staged bf16 into LDS [192][72]
// (pad to 72 elems / 144B row stride: uniform bank coverage for b128 reads).
// 2 barriers/step; loads issued at top of step, LDS-written after compute
// (compiler's own vmcnt-before-ds_write gives issue-early/write-late).
// Wave (wm=w>>1, wn=w&1): rows wm*16..+16, col-tiles T = wn*6+nt (12 tiles of 16).
// q stored [B*S][64] bf16 PRE-SCALED by 0.125*log2e; k [B*S][64]; v transposed
// vt[b][h][s]. Also emits pen[b][2][S] f32 (penA/penP additive mask rows).
__global__ __launch_bounds__(512, 4) void k_proj(const float* __restrict__ hs,
                                                 const float* __restrict__ bq,
                                                 const float* __restrict__ bk,
                                                 const float* __restrict__ bv,
                                                 const ushort_t* __restrict__ Wt,
                                                 const int* __restrict__ am,
                                                 ushort_t* __restrict__ q,
                                                 ushort_t* __restrict__ k,
                                                 ushort_t* __restrict__ vt,
                                                 float* __restrict__ pen) {
  __shared__ __align__(16) ushort_t bufA[2][64][72];   // 18 KB
  __shared__ __align__(16) ushort_t bufW[2][192][72];  // 54 KB

  int t = threadIdx.x, w = t >> 6, l = t & 63, g = l >> 4, c = l & 15;
  int wm = w >> 1, wn = w & 1;
  int row0 = blockIdx.x * 64;

  // staging indices (512 threads)
  int ar = t >> 3, ach = t & 7;          // A: row 0..63, 16B-chunk 0..7
  const float* agp = hs + (size_t)(row0 + ar) * Ee + ach * 8;
  const ushort_t* wgp = Wt + (size_t)(t >> 3) * Ee + (t & 7) * 8;  // j*512 rows later

  f32x4 acc[6];
#pragma unroll
  for (int nt = 0; nt < 6; ++nt) acc[nt] = f32x4{0.f, 0.f, 0.f, 0.f};

  float4 aR0, aR1;
  u32x4 wR[3];

  auto LOAD = [&](int kk) {
    aR0 = *reinterpret_cast<const float4*>(agp + kk);
    aR1 = *reinterpret_cast<const float4*>(agp + kk + 4);
#pragma unroll
    for (int j = 0; j < 3; ++j)
      wR[j] = *reinterpret_cast<const u32x4*>(wgp + (size_t)j * 64 * Ee + kk);
  };
  auto WRITE = [&](int buf) {
    bf16x8 av;
    av[0] = (__bf16)aR0.x; av[1] = (__bf16)aR0.y; av[2] = (__bf16)aR0.z; av[3] = (__bf16)aR0.w;
    av[4] = (__bf16)aR1.x; av[5] = (__bf16)aR1.y; av[6] = (__bf16)aR1.z; av[7] = (__bf16)aR1.w;
    *reinterpret_cast<bf16x8*>(&bufA[buf][ar][ach * 8]) = av;
#pragma unroll
    for (int j = 0; j < 3; ++j)
      *reinterpret_cast<u32x4*>(&bufW[buf][(t >> 3) + j * 64][(t & 7) * 8]) = wR[j];
  };
  auto COMPUTE = [&](int buf) {
    const ushort_t* Ab = &bufA[buf][wm * 16 + c][0];
    bf16x8 af0 = *reinterpret_cast<const bf16x8*>(Ab + g * 8);
    bf16x8 af1 = *reinterpret_cast<const bf16x8*>(Ab + 32 + g * 8);
#pragma unroll
    for (int nt = 0; nt < 6; ++nt) {
      const ushort_t* Wb = &bufW[buf][wn * 96 + nt * 16 + c][0];
      bf16x8 b0 = *reinterpret_cast<const bf16x8*>(Wb + g * 8);
      bf16x8 b1 = *reinterpret_cast<const bf16x8*>(Wb + 32 + g * 8);
      acc[nt] = mfma16(af0, b0, acc[nt]);
      acc[nt] = mfma16(af1, b1, acc[nt]);
    }
  };

  // prologue
  LOAD(0);
  WRITE(0);
  __syncthreads();

  int cur = 0;
  for (int s = 0; s < 16; ++s) {
    if (s < 15) LOAD((s + 1) * 64);   // issue next tile's loads early
    COMPUTE(cur);
    if (s < 15) {
      __syncthreads();                // everyone done reading buf[cur^1] (step s-1)
      WRITE(cur ^ 1);                 // compiler inserts vmcnt before these ds_writes
      __syncthreads();                // buf[cur^1] ready
      cur ^= 1;
    }
  }

  // epilogue: T = wn*6+nt -> m = T>>2 (q/k/v), h = (T&3)*16+c; rows wm*16+g*4+i
#pragma unroll
  for (int nt = 0; nt < 6; ++nt) {
    int T = wn * 6 + nt;
    int m = T >> 2;
    int h = (T & 3) * 16 + c;
    const float* bias = (m == 0) ? bq : ((m == 1) ? bk : bv);
    float bb = bias[h];
#pragma unroll
    for (int i = 0; i < 4; ++i) {
      int row = row0 + wm * 16 + g * 4 + i;
      float val = acc[nt][i] + bb;
      if (m == 0) {
        q[(size_t)row * Hh + h] = f2bfu(val * SCLQ);
      } else if (m == 1) {
        k[(size_t)row * Hh + h] = f2bfu(val);
      } else {
        int bi = row >> 11, s2 = row & 2047;
        vt[((size_t)(bi * 64 + h)) * Ss + s2] = f2bfu(val);
      }
    }
  }

  if (t < 64) {
    int grow = row0 + t;
    int bi = grow >> 11, s2 = grow & 2047;
    int mv = am[grow];
    pen[((size_t)bi * 2 + 0) * Ss + s2] = mv ? 0.f : NEG2;
    pen[((size_t)bi * 2 + 1) * Ss + s2] = mv ? NEG2 : 0.f;
  }
}

// ---------------- fused masked flash attention, swapped-QK 32x32, in-register softmax ----
// Block: 32 q-rows of one batch, 4 waves split keys (512 each, 16 tiles of 32).
// Lane owns one q-row (lo = l&31): softmax = 15 in-lane max/sum + 1 cross-half shfl.
// P -> PV A-frags via 8 cvt_pk + 4 permlane32_swap. Defer-max (T13) makes O-rescale rare.
__global__ __launch_bounds__(256) void k_attn(const ushort_t* __restrict__ qs,
                                              const ushort_t* __restrict__ km,
                                              const ushort_t* __restrict__ vt,
                                              const int* __restrict__ am,
                                              const float* __restrict__ pen,
                                              float* __restrict__ out) {
  __shared__ float obuf[4][32][64];
  __shared__ float mls[4][32], lls[4][32];

  int t = threadIdx.x, w = t >> 6, l = t & 63, lo = l & 31, hi = l >> 5;
  int b = blockIdx.y, q0 = blockIdx.x * 32;

  // Q B-frags (hoisted): lane holds Q[q0+lo][c*16 + hi*8 + j]
  const ushort_t* qp = qs + ((size_t)(b * Ss + q0 + lo)) * Hh + hi * 8;
  bf16x8 qf[4];
#pragma unroll
  for (int c = 0; c < 4; ++c) qf[c] = *reinterpret_cast<const bf16x8*>(qp + c * 16);

  int mq = am[b * Ss + q0 + lo];
  float negq = mq ? NEG2 : 0.f;
  const float* psel = pen + ((size_t)b * 2 + (mq ? 0 : 1)) * Ss;

  float m = -3.0e38f, ll = 0.f;
  f32x16 o0 = {0.f, 0.f, 0.f, 0.f, 0.f, 0.f, 0.f, 0.f, 0.f, 0.f, 0.f, 0.f, 0.f, 0.f, 0.f, 0.f};
  f32x16 o1 = o0;
  const f32x16 z16 = o0;

  const int kvbeg = w * 512;
  for (int it = 0; it < 16; ++it) {
    int kv0 = kvbeg + it * 32;

    // K A-frags: lane holds K[kv0+lo][c*16 + hi*8 + j]
    const ushort_t* kp = km + ((size_t)(b * Ss + kv0 + lo)) * Hh + hi * 8;
    bf16x8 kf0 = *reinterpret_cast<const bf16x8*>(kp);
    bf16x8 kf1 = *reinterpret_cast<const bf16x8*>(kp + 16);
    bf16x8 kf2 = *reinterpret_cast<const bf16x8*>(kp + 32);
    bf16x8 kf3 = *reinterpret_cast<const bf16x8*>(kp + 48);

    // V B-frags: lane holds V[kv0 + c2*16 + hi*8 + j][dt*32 + lo] from vt[b][d][s]
    const ushort_t* vp0 = vt + ((size_t)(b * 64 + lo)) * Ss + kv0 + hi * 8;
    const ushort_t* vp1 = vt + ((size_t)(b * 64 + 32 + lo)) * Ss + kv0 + hi * 8;
    bf16x8 vf00 = *reinterpret_cast<const bf16x8*>(vp0);
    bf16x8 vf10 = *reinterpret_cast<const bf16x8*>(vp0 + 16);
    bf16x8 vf01 = *reinterpret_cast<const bf16x8*>(vp1);
    bf16x8 vf11 = *reinterpret_cast<const bf16x8*>(vp1 + 16);

    // penalty vectors: reg r -> key kv0 + (r&3) + 8*(r>>2) + 4*hi
    f32x4 pv[4];
#pragma unroll
    for (int j = 0; j < 4; ++j)
      pv[j] = *reinterpret_cast<const f32x4*>(psel + kv0 + j * 8 + hi * 4);

    // ---- scores: D[key][q], key = (r&3)+8*(r>>2)+4*hi, q = lo ----
    f32x16 sc = mfma32(kf0, qf[0], z16);
    sc = mfma32(kf1, qf[1], sc);
    sc = mfma32(kf2, qf[2], sc);
    sc = mfma32(kf3, qf[3], sc);

    if (kv0 == q0) {  // straddle tile: per-reg causal
#pragma unroll
      for (int r = 0; r < 16; ++r) {
        int kr = (r & 3) + 8 * (r >> 2) + 4 * hi;
        float pc = (kr > lo) ? negq : 0.f;
        sc[r] += pv[r >> 2][r & 3] + pc;
      }
    } else {
      float addt = (kv0 > q0) ? negq : 0.f;
#pragma unroll
      for (int r = 0; r < 16; ++r) sc[r] += pv[r >> 2][r & 3] + addt;
    }

    // ---- row max (in-lane tree + cross-half shfl) ----
    float pm01 = fmaxf(sc[0], sc[1]), pm23 = fmaxf(sc[2], sc[3]);
    float pm45 = fmaxf(sc[4], sc[5]), pm67 = fmaxf(sc[6], sc[7]);
    float pm89 = fmaxf(sc[8], sc[9]), pmab = fmaxf(sc[10], sc[11]);
    float pmcd = fmaxf(sc[12], sc[13]), pmef = fmaxf(sc[14], sc[15]);
    float pm = fmaxf(fmaxf(fmaxf(pm01, pm23), fmaxf(pm45, pm67)),
                     fmaxf(fmaxf(pm89, pmab), fmaxf(pmcd, pmef)));
    pm = fmaxf(pm, __shfl_xor(pm, 32));

    // ---- defer-max: rescale only when the running max grows past THR2 ----
    if (!__all(pm <= m + THR2)) {
      float mn = fmaxf(m, pm);
      float alpha = __builtin_amdgcn_exp2f(m - mn);
      m = mn;
      ll *= alpha;
      int ia = __builtin_bit_cast(int, alpha);
#pragma unroll
      for (int r = 0; r < 16; ++r) {
        int qrow = (r & 3) + 8 * (r >> 2) + 4 * hi;
        float af = __builtin_bit_cast(float, __builtin_amdgcn_ds_bpermute(qrow << 2, ia));
        o0[r] *= af;
        o1[r] *= af;
      }
    }

    // ---- p = exp2(sc - m), row sum ----
    float p[16];
    float ts = 0.f;
#pragma unroll
    for (int r = 0; r < 16; ++r) {
      p[r] = __builtin_amdgcn_exp2f(sc[r] - m);
      ts += p[r];
    }
    ts += __shfl_xor(ts, 32);
    ll += ts;

    // ---- P -> PV A-frags: 8 cvt_pk + 4 permlane32_swap (distinct values: safe) ----
    unsigned x0 = cvtpk(p[0], p[1]), y0 = cvtpk(p[2], p[3]);
    unsigned z0 = cvtpk(p[4], p[5]), w0 = cvtpk(p[6], p[7]);
    swap32(x0, z0);
    swap32(y0, w0);
    unsigned x1 = cvtpk(p[8], p[9]), y1 = cvtpk(p[10], p[11]);
    unsigned z1 = cvtpk(p[12], p[13]), w1 = cvtpk(p[14], p[15]);
    swap32(x1, z1);
    swap32(y1, w1);
    bf16x8 pa0 = __builtin_bit_cast(bf16x8, u32x4{x0, y0, z0, w0});
    bf16x8 pa1 = __builtin_bit_cast(bf16x8, u32x4{x1, y1, z1, w1});

    // ---- PV: D[q][d] ----
    o0 = mfma32(pa0, vf00, o0);
    o0 = mfma32(pa1, vf10, o0);
    o1 = mfma32(pa0, vf01, o1);
    o1 = mfma32(pa1, vf11, o1);
  }

  // ---- stash partials ----
#pragma unroll
  for (int r = 0; r < 16; ++r) {
    int qrow = (r & 3) + 8 * (r >> 2) + 4 * hi;
    obuf[w][qrow][lo] = o0[r];
    obuf[w][qrow][32 + lo] = o1[r];
  }
  if (hi == 0) {
    mls[w][lo] = m;
    lls[w][lo] = ll;
  }
  __syncthreads();

  // ---- combine 4 KV-split partials: thread -> (qrow = t>>3, 8 d-cols) ----
  int qr = t >> 3, dg = t & 7;
  float mg = fmaxf(fmaxf(mls[0][qr], mls[1][qr]), fmaxf(mls[2][qr], mls[3][qr]));
  float lg = 0.f, sw[4];
#pragma unroll
  for (int ww = 0; ww < 4; ++ww) {
    sw[ww] = __builtin_amdgcn_exp2f(mls[ww][qr] - mg);
    lg += lls[ww][qr] * sw[ww];
  }
  float a8[8] = {0.f, 0.f, 0.f, 0.f, 0.f, 0.f, 0.f, 0.f};
#pragma unroll
  for (int ww = 0; ww < 4; ++ww) {
    float4 c0 = *reinterpret_cast<const float4*>(&obuf[ww][qr][dg * 8]);
    float4 c1 = *reinterpret_cast<const float4*>(&obuf[ww][qr][dg * 8 + 4]);
    a8[0] += c0.x * sw[ww]; a8[1] += c0.y * sw[ww];
    a8[2] += c0.z * sw[ww]; a8[3] += c0.w * sw[ww];
    a8[4] += c1.x * sw[ww]; a8[5] += c1.y * sw[ww];
    a8[6] += c1.z * sw[ww]; a8[7] += c1.w * sw[ww];
  }
  float inv = 1.f / lg;
  float4 r0 = {a8[0] * inv, a8[1] * inv, a8[2] * inv, a8[3] * inv};
  float4 r1 = {a8[4] * inv, a8[5] * inv, a8[6] * inv, a8[7] * inv};
  float* op = out + ((size_t)(b * Ss + q0 + qr)) * Hh + dg * 8;
  *reinterpret_cast<float4*>(op) = r0;
  *reinterpret_cast<float4*>(op + 4) = r1;
}

extern "C" void kernel_launch(void* const* d_in, const int* in_sizes, int n_in,
                              void* d_out, int out_size, void* d_ws, size_t ws_size,
                              hipStream_t stream) {
  const float* hs = (const float*)d_in[0];
  const int* am = (const int*)d_in[1];
  const float* Wq = (const float*)d_in[2];
  const float* bq = (const float*)d_in[3];
  const float* Wk = (const float*)d_in[4];
  const float* bk = (const float*)d_in[5];
  const float* Wv = (const float*)d_in[6];
  const float* bv = (const float*)d_in[7];
  float* out = (float*)d_out;

  char* ws = (char*)d_ws;
  ushort_t* qsp = (ushort_t*)(ws + 0);                  // 2 MB: [B*S][64] bf16, scaled
  ushort_t* kp = (ushort_t*)(ws + (2u << 20));          // 2 MB: [B*S][64] bf16
  ushort_t* vtp = (ushort_t*)(ws + (4u << 20));         // 2 MB: [B][64][S] bf16 (V^T)
  ushort_t* wtp = (ushort_t*)(ws + (6u << 20));         // 384 KB: [3][64][1024] bf16 (W^T)
  float* penp = (float*)(ws + (6u << 20) + (512u << 10));  // 128 KB: [B][2][S] f32

  k_wtrans<<<dim3(16, 3), 256, 0, stream>>>(Wq, Wk, Wv, wtp);
  k_proj<<<dim3(256), 512, 0, stream>>>(hs, bq, bk, bv, wtp, am, qsp, kp, vtp, penp);
  k_attn<<<dim3(64, 8), 256, 0, stream>>>(qsp, kp, vtp, am, penp, out);
}